// Round 1
// baseline (1918.458 us; speedup 1.0000x reference)
//
#include <hip/hip_runtime.h>
#include <hip/hip_bf16.h>

#define S_DIM 2048
#define DV_DIM 64
#define NEGV (-1000000000.0f)

typedef __bf16 bf16x8 __attribute__((ext_vector_type(8)));
typedef float  f32x4  __attribute__((ext_vector_type(4)));

#define MFMA(a, b, c) __builtin_amdgcn_mfma_f32_16x16x32_bf16(a, b, c, 0, 0, 0)

// Block: 16 rows of one (b,h). 8 waves x 256 cols each. Scores live in MFMA
// C-frags (16 tiles x f32x4 = 64 VGPR/lane). Exact softmax via shuffle + LDS
// cross-wave reduction. attn written fp32 from regs; LDS roundtrip (bf16) for
// the C-layout -> A-layout transform feeding the PV MFMAs.
__global__ __launch_bounds__(512, 2)
void fra_kernel(const float* __restrict__ vptr,
                const int*   __restrict__ mask,
                const float* __restrict__ a1,
                const float* __restrict__ a2,
                float* __restrict__ out,
                float* __restrict__ attn)
{
    const int tid  = threadIdx.x;
    const int wv   = tid >> 6;
    const int lane = tid & 63;
    const int q    = lane >> 4;
    const int ln   = lane & 15;

    // XCD-grouped swizzle: each XCD (blockIdx%8) works consecutive row-tiles
    // of the same bh for a2/v L2 reuse.
    const int idx  = blockIdx.x;
    const int w    = (idx & 7) * 1024 + (idx >> 3);
    const int bh   = w >> 7;
    const int row0 = (w & 127) << 4;

    __shared__ float redmax[8][16];
    __shared__ float redsum[8][16];
    // per-wave private: 16 rows x 128 cols bf16 (+8 pad -> stride 136 = 272B,
    // 16B-aligned rows, ~2-way LDS banking). Reused as fp32 out staging
    // (stride 68 floats) at the end.
    __shared__ __align__(16) __bf16 pbuf[8][16][136];

    // ---- a1 fragments, hi/lo split (error ~2^-18 after split) ----
    const float* a1p = a1 + ((size_t)bh * S_DIM + row0 + ln) * 64 + q * 8;
    bf16x8 a1hi[2], a1lo[2];
#pragma unroll
    for (int kb = 0; kb < 2; ++kb) {
        const float4 f0 = *(const float4*)(a1p + kb * 32);
        const float4 f1 = *(const float4*)(a1p + kb * 32 + 4);
        float tf[8] = {f0.x, f0.y, f0.z, f0.w, f1.x, f1.y, f1.z, f1.w};
#pragma unroll
        for (int j = 0; j < 8; ++j) {
            __bf16 h = (__bf16)tf[j];
            __bf16 l = (__bf16)(tf[j] - (float)h);
            a1hi[kb][j] = h;
            a1lo[kb][j] = l;
        }
    }

    // ---- scores: 16 tiles of 16 cols, K=64 in two 32-chunks, split-MFMA ----
    f32x4 acc[16];
#pragma unroll
    for (int ct = 0; ct < 16; ++ct) acc[ct] = f32x4{0.f, 0.f, 0.f, 0.f};

    const int cbase = wv * 256;
    const float* a2p = a2 + (size_t)bh * 64 * S_DIM + (size_t)(q * 8) * S_DIM + ln;

#pragma unroll
    for (int ct = 0; ct < 16; ++ct) {
        const int c0 = cbase + ct * 16;
        bf16x8 bhi[2], blo[2];
#pragma unroll
        for (int kb = 0; kb < 2; ++kb) {
#pragma unroll
            for (int j = 0; j < 8; ++j) {
                float fv = a2p[(size_t)(kb * 32 + j) * S_DIM + c0];
                __bf16 h = (__bf16)fv;
                __bf16 l = (__bf16)(fv - (float)h);
                bhi[kb][j] = h;
                blo[kb][j] = l;
            }
        }
        acc[ct] = MFMA(a1hi[0], bhi[0], acc[ct]);
        acc[ct] = MFMA(a1hi[1], bhi[1], acc[ct]);
        acc[ct] = MFMA(a1lo[0], bhi[0], acc[ct]);
        acc[ct] = MFMA(a1lo[1], bhi[1], acc[ct]);
        acc[ct] = MFMA(a1hi[0], blo[0], acc[ct]);
        acc[ct] = MFMA(a1hi[1], blo[1], acc[ct]);
    }

    // ---- mask + local row max (C layout: row = q*4+rr, col = ln) ----
    const int* mp = mask + ((size_t)(bh >> 3) * S_DIM + row0 + q * 4) * S_DIM + cbase + ln;
    float lmax[4] = {NEGV, NEGV, NEGV, NEGV};
#pragma unroll
    for (int ct = 0; ct < 16; ++ct) {
#pragma unroll
        for (int rr = 0; rr < 4; ++rr) {
            int mv = mp[(size_t)rr * S_DIM + ct * 16];
            float s = mv ? acc[ct][rr] : NEGV;
            acc[ct][rr] = s;
            lmax[rr] = fmaxf(lmax[rr], s);
        }
    }
#pragma unroll
    for (int off = 8; off >= 1; off >>= 1) {
#pragma unroll
        for (int rr = 0; rr < 4; ++rr)
            lmax[rr] = fmaxf(lmax[rr], __shfl_xor(lmax[rr], off, 64));
    }
    if (ln == 0) {
#pragma unroll
        for (int rr = 0; rr < 4; ++rr) redmax[wv][q * 4 + rr] = lmax[rr];
    }
    __syncthreads();
    float rmax[4];
#pragma unroll
    for (int rr = 0; rr < 4; ++rr) {
        float m = redmax[0][q * 4 + rr];
#pragma unroll
        for (int w8 = 1; w8 < 8; ++w8) m = fmaxf(m, redmax[w8][q * 4 + rr]);
        rmax[rr] = m;
    }

    // ---- exp + row sum ----
    float lsum[4] = {0.f, 0.f, 0.f, 0.f};
#pragma unroll
    for (int ct = 0; ct < 16; ++ct) {
#pragma unroll
        for (int rr = 0; rr < 4; ++rr) {
            float p = __expf(acc[ct][rr] - rmax[rr]);
            acc[ct][rr] = p;
            lsum[rr] += p;
        }
    }
#pragma unroll
    for (int off = 8; off >= 1; off >>= 1) {
#pragma unroll
        for (int rr = 0; rr < 4; ++rr)
            lsum[rr] += __shfl_xor(lsum[rr], off, 64);
    }
    if (ln == 0) {
#pragma unroll
        for (int rr = 0; rr < 4; ++rr) redsum[wv][q * 4 + rr] = lsum[rr];
    }
    __syncthreads();
    float rinv[4];
#pragma unroll
    for (int rr = 0; rr < 4; ++rr) {
        float s2 = redsum[0][q * 4 + rr];
#pragma unroll
        for (int w8 = 1; w8 < 8; ++w8) s2 += redsum[w8][q * 4 + rr];
        rinv[rr] = 1.0f / s2;
    }

    // ---- normalize + store attn + PV (two 128-col chunks) ----
    float* attnp = attn + ((size_t)bh * S_DIM + row0 + q * 4) * S_DIM + cbase + ln;
    const float* vp = vptr + (size_t)bh * S_DIM * DV_DIM + (size_t)(cbase + q * 8) * DV_DIM + ln;

    f32x4 oacc[4];
#pragma unroll
    for (int nt = 0; nt < 4; ++nt) oacc[nt] = f32x4{0.f, 0.f, 0.f, 0.f};

#pragma unroll
    for (int ch = 0; ch < 2; ++ch) {
#pragma unroll
        for (int t8 = 0; t8 < 8; ++t8) {
            const int ct = ch * 8 + t8;
#pragma unroll
            for (int rr = 0; rr < 4; ++rr) {
                float a = acc[ct][rr] * rinv[rr];
                attnp[(size_t)rr * S_DIM + ct * 16] = a;           // fp32 output
                pbuf[wv][q * 4 + rr][t8 * 16 + ln] = (__bf16)a;    // for PV
            }
        }
        __syncthreads();
#pragma unroll
        for (int kc = 0; kc < 4; ++kc) {
            // A-frag: A[m=ln][k=q*8+j] -> contiguous 16B in pbuf row ln
            bf16x8 af = *(const bf16x8*)&pbuf[wv][ln][kc * 32 + q * 8];
#pragma unroll
            for (int nt = 0; nt < 4; ++nt) {
                bf16x8 bf;
#pragma unroll
                for (int j = 0; j < 8; ++j)
                    bf[j] = (__bf16)vp[(size_t)(ch * 128 + kc * 32 + j) * DV_DIM + nt * 16];
                oacc[nt] = MFMA(af, bf, oacc[nt]);
            }
        }
        __syncthreads();
    }

    // ---- cross-wave out reduction via LDS (reuse pbuf as fp32, stride 68) ----
    float* ob = (float*)&pbuf[wv][0][0];
#pragma unroll
    for (int nt = 0; nt < 4; ++nt) {
#pragma unroll
        for (int rr = 0; rr < 4; ++rr)
            ob[(q * 4 + rr) * 68 + nt * 16 + ln] = oacc[nt][rr];
    }
    __syncthreads();

#pragma unroll
    for (int i = 0; i < 2; ++i) {
        int e = tid + i * 512;
        int r = e >> 6, c = e & 63;
        float s = 0.f;
#pragma unroll
        for (int w8 = 0; w8 < 8; ++w8)
            s += ((const float*)&pbuf[w8][0][0])[r * 68 + c];
        out[((size_t)bh * S_DIM + row0 + r) * DV_DIM + c] = s;
    }
}

extern "C" void kernel_launch(void* const* d_in, const int* in_sizes, int n_in,
                              void* d_out, int out_size, void* d_ws, size_t ws_size,
                              hipStream_t stream) {
    const float* v    = (const float*)d_in[0];
    const int*   mask = (const int*)d_in[1];
    const float* a1   = (const float*)d_in[2];
    const float* a2   = (const float*)d_in[3];
    // d_in[4] = len_q (== S, constant) — unused.

    float* out  = (float*)d_out;
    float* attn = out + (size_t)8 * 8 * 2048 * 64;  // out is 8.39M floats, attn follows

    fra_kernel<<<8192, 512, 0, stream>>>(v, mask, a1, a2, out, attn);
}